// Round 11
// baseline (9261.354 us; speedup 1.0000x reference)
//
#include <hip/hip_runtime.h>
#include <stdint.h>

// ---------------------------------------------------------------------------
// BondMatrixMessage: messages[b,e,i] = sum_{k,j} bond[b,e,k] W[k,i,j] src[b,e,j]
// GEMM recast: C[16384 x 64] = A[16384 x 4096] @ W2[4096 x 64]
// R11: ABLATION ROUND. Production path (prep + R10 bond_msg -> d_out) is
// unchanged. Four REPS=48 diagnostic kernels (template<MODE>) run after it,
// writing to scratch (w2f region; prep rewrites it every replay):
//   MODE 0 (A): full loop      = gll + vmcnt + ds_read + A-gen + MFMA
//   MODE 1 (B): no gll         =                ds_read + A-gen + MFMA
//   MODE 2 (C): no ds_read     = gll + vmcnt +            A-gen + MFMA(regs)
//   MODE 3 (D): compute only   =                           A-gen + MFMA(regs)
// Each > 40 us -> all visible in rocprof top-5 with real counters.
// LICM defeated by rep-dependent opaque acc-init (oz ^ rep); REPS state kept
// small (R8 spill lesson); runtime-constant indices only (rule #20).
// conn is int32 (harness narrows int64): src idx = conn[e*2].
// ---------------------------------------------------------------------------

#define NATOMS 256
#define DIM 64
#define BM 64
#define DREPS 48

typedef _Float16 f16;
typedef _Float16 f16x2 __attribute__((ext_vector_type(2)));
typedef _Float16 f16x8 __attribute__((ext_vector_type(8)));
typedef float f32x16 __attribute__((ext_vector_type(16)));

#define AS1 __attribute__((address_space(1)))
#define AS3 __attribute__((address_space(3)))

union H8 { f16x8 v8; f16x2 v2[4]; };

static __device__ __forceinline__ void gll16(const void* g, void* l) {
    __builtin_amdgcn_global_load_lds((AS1 void*)(uintptr_t)g, (AS3 void*)l, 16, 0, 0);
}

// prep: cast + permute bt (64 x 4096 f32) into fragment-ordered f16 chunks.
__global__ __launch_bounds__(256) void prep_w2f(const float* __restrict__ bt,
                                                f16* __restrict__ w2f) {
    const int d  = blockIdx.x * 256 + threadIdx.x;   // 32768 chunks
    const int kg = d >> 9, c = d & 511;
    const int wcq = c >> 8, s = (c >> 6) & 3, l = c & 63;
    const int i = (l & 31) + 32 * wcq;
    const int u = 2 * s + (l >> 5);
    const float* src = bt + (size_t)kg * 4096 + i * 64 + u * 8;
    const float4 p = *reinterpret_cast<const float4*>(src);
    const float4 q = *reinterpret_cast<const float4*>(src + 4);
    const f16x8 h = { (f16)p.x, (f16)p.y, (f16)p.z, (f16)p.w,
                      (f16)q.x, (f16)q.y, (f16)q.z, (f16)q.w };
    reinterpret_cast<f16x8*>(w2f)[d] = h;
}

static __device__ __forceinline__ unsigned swz16(unsigned lane) {
    return (lane * 16u) ^ ((lane & 0x38u) << 1);
}

// =================== production kernel (identical to R10) ===================
__global__ __launch_bounds__(512, 1) void bond_msg(
    const float* __restrict__ atom, const float* __restrict__ bond,
    const int* __restrict__ conn, const f16* __restrict__ w2f,
    float* __restrict__ out)
{
    __shared__ __align__(16) unsigned char smem[131072];

    const int tid  = threadIdx.x;
    const int lane = tid & 63;
    const int w    = tid >> 6;
    const int wc   = w & 1;
    const int kq   = w >> 1;
    const int lo   = lane & 31;
    const int hi   = lane >> 5;
    const int blk  = blockIdx.x;
    const int bond0 = blk * BM;

    const int m0 = lo, m1 = lo + 32;
    const int ia0 = conn[(bond0 + m0) * 2];
    const int ia1 = conn[(bond0 + m1) * 2];

    const char* gw = reinterpret_cast<const char*>(w2f)
                   + (size_t)(kq * 16) * 8192 + wc * 4096 + lane * 16;
    char* lsta = reinterpret_cast<char*>(smem) + w * 16384;
    const char* lread = reinterpret_cast<const char*>(smem) + w * 16384 + lane * 16;

    #define ISSUE(itf) do {                                               \
        const char* _g = gw + (itf) * 8192;                               \
        char* _l = lsta + ((itf) & 3) * 4096;                             \
        gll16(_g,        _l);                                             \
        gll16(_g + 1024, _l + 1024);                                      \
        gll16(_g + 2048, _l + 2048);                                      \
        gll16(_g + 3072, _l + 3072);                                      \
    } while (0)

    ISSUE(0); ISSUE(1); ISSUE(2);

    f16x2 bp0[16], bp1[16];
    {
        const float* br0 = bond + (size_t)(bond0 + m0) * DIM + kq * 16;
        const float* br1 = bond + (size_t)(bond0 + m1) * DIM + kq * 16;
        #pragma unroll
        for (int q = 0; q < 4; ++q) {
            const float4 v0 = *reinterpret_cast<const float4*>(br0 + q * 4);
            const float4 v1 = *reinterpret_cast<const float4*>(br1 + q * 4);
            const f16 a0 = (f16)v0.x, a1 = (f16)v0.y, a2 = (f16)v0.z, a3 = (f16)v0.w;
            const f16 c0 = (f16)v1.x, c1 = (f16)v1.y, c2 = (f16)v1.z, c3 = (f16)v1.w;
            bp0[q*4+0] = (f16x2){a0,a0}; bp0[q*4+1] = (f16x2){a1,a1};
            bp0[q*4+2] = (f16x2){a2,a2}; bp0[q*4+3] = (f16x2){a3,a3};
            bp1[q*4+0] = (f16x2){c0,c0}; bp1[q*4+1] = (f16x2){c1,c1};
            bp1[q*4+2] = (f16x2){c2,c2}; bp1[q*4+3] = (f16x2){c3,c3};
        }
    }

    const float* ar0 = atom + (size_t)(blk >> 3) * (NATOMS * DIM) + (size_t)ia0 * DIM;
    const float* ar1 = atom + (size_t)(blk >> 3) * (NATOMS * DIM) + (size_t)ia1 * DIM;
    f16x2 srcv[2][4][4];
    #pragma unroll
    for (int s = 0; s < 4; ++s) {
        const int j0 = s * 16 + hi * 8;
        float4 p0 = *reinterpret_cast<const float4*>(ar0 + j0);
        float4 p1 = *reinterpret_cast<const float4*>(ar0 + j0 + 4);
        float4 q0 = *reinterpret_cast<const float4*>(ar1 + j0);
        float4 q1 = *reinterpret_cast<const float4*>(ar1 + j0 + 4);
        srcv[0][s][0] = (f16x2){ (f16)p0.x, (f16)p0.y };
        srcv[0][s][1] = (f16x2){ (f16)p0.z, (f16)p0.w };
        srcv[0][s][2] = (f16x2){ (f16)p1.x, (f16)p1.y };
        srcv[0][s][3] = (f16x2){ (f16)p1.z, (f16)p1.w };
        srcv[1][s][0] = (f16x2){ (f16)q0.x, (f16)q0.y };
        srcv[1][s][1] = (f16x2){ (f16)q0.z, (f16)q0.w };
        srcv[1][s][2] = (f16x2){ (f16)q1.x, (f16)q1.y };
        srcv[1][s][3] = (f16x2){ (f16)q1.z, (f16)q1.w };
    }

    f32x16 acc0 = {}, acc1 = {};

    #define STEP(iti, wtxt) do {                                          \
        if ((iti) + 3 < 16) ISSUE((iti) + 3);                             \
        H8 _af0[4], _af1[4];                                              \
        {                                                                 \
            const f16x2 _c0 = bp0[iti];                                   \
            const f16x2 _c1 = bp1[iti];                                   \
            _Pragma("unroll")                                             \
            for (int s = 0; s < 4; ++s) {                                 \
                _Pragma("unroll")                                         \
                for (int t = 0; t < 4; ++t) {                             \
                    _af0[s].v2[t] = _c0 * srcv[0][s][t];                  \
                    _af1[s].v2[t] = _c1 * srcv[1][s][t];                  \
                }                                                         \
            }                                                             \
        }                                                                 \
        asm volatile("s_waitcnt vmcnt(" wtxt ")" ::: "memory");           \
        __builtin_amdgcn_sched_barrier(0);                                \
        {                                                                 \
            const char* _lr = lread + ((iti) & 3) * 4096;                 \
            _Pragma("unroll")                                             \
            for (int s = 0; s < 4; ++s) {                                 \
                const f16x8 bf = *reinterpret_cast<const f16x8*>(_lr + s * 1024); \
                acc0 = __builtin_amdgcn_mfma_f32_32x32x16_f16(_af0[s].v8, bf, acc0, 0, 0, 0); \
                acc1 = __builtin_amdgcn_mfma_f32_32x32x16_f16(_af1[s].v8, bf, acc1, 0, 0, 0); \
            }                                                             \
        }                                                                 \
    } while (0)

    STEP( 0, "12"); STEP( 1, "12"); STEP( 2, "12"); STEP( 3, "12");
    STEP( 4, "12"); STEP( 5, "12"); STEP( 6, "12"); STEP( 7, "12");
    STEP( 8, "12"); STEP( 9, "12"); STEP(10, "12"); STEP(11, "12");
    STEP(12, "12"); STEP(13, "8");  STEP(14, "4");  STEP(15, "0");

    #undef STEP
    #undef ISSUE

    __syncthreads();
    {
        const unsigned wbase = (unsigned)w * 8192u;
        const unsigned so = swz16((unsigned)lane);
        #pragma unroll
        for (int g = 0; g < 4; ++g) {
            float4 v0 = { acc0[4*g+0], acc0[4*g+1], acc0[4*g+2], acc0[4*g+3] };
            *reinterpret_cast<float4*>(smem + wbase + g*1024 + so) = v0;
            float4 v1 = { acc1[4*g+0], acc1[4*g+1], acc1[4*g+2], acc1[4*g+3] };
            *reinterpret_cast<float4*>(smem + wbase + (g+4)*1024 + so) = v1;
        }
    }
    __syncthreads();
    {
        const int c  = tid & 63;
        const int rb = tid >> 6;
        const int a  = rb >> 2, g = rb & 3;
        const unsigned colb = (unsigned)(c & 31);
        const unsigned wcs  = (unsigned)(c >> 5);
        const unsigned o0 = swz16(colb);
        const unsigned o1 = swz16(32u + colb);
        float4 s0 = {0.f,0.f,0.f,0.f}, s1 = {0.f,0.f,0.f,0.f};
        #pragma unroll
        for (int q = 0; q < 4; ++q) {
            const unsigned base = (unsigned)((q*2 + wcs) * 8192 + (a*4+g) * 1024);
            const float4 u0 = *reinterpret_cast<const float4*>(smem + base + o0);
            const float4 u1 = *reinterpret_cast<const float4*>(smem + base + o1);
            s0.x += u0.x; s0.y += u0.y; s0.z += u0.z; s0.w += u0.w;
            s1.x += u1.x; s1.y += u1.y; s1.z += u1.z; s1.w += u1.w;
        }
        float* orow = out + (size_t)(bond0 + 32*a + 8*g) * 64 + c;
        orow[0*64] = s0.x; orow[1*64] = s0.y; orow[2*64] = s0.z; orow[3*64] = s0.w;
        orow[4*64] = s1.x; orow[5*64] = s1.y; orow[6*64] = s1.z; orow[7*64] = s1.w;
    }
}

// =================== diagnostic kernels (ablation) ===================
template<int MODE>
__global__ __launch_bounds__(512, 1) void bond_diag(
    const float* __restrict__ atom, const float* __restrict__ bond,
    const int* __restrict__ conn, const f16* __restrict__ w2f,
    float* __restrict__ sink)
{
    __shared__ __align__(16) unsigned char smem[131072];

    const int tid  = threadIdx.x;
    const int lane = tid & 63;
    const int w    = tid >> 6;
    const int wc   = w & 1;
    const int kq   = w >> 1;
    const int lo   = lane & 31;
    const int hi   = lane >> 5;
    const int blk  = blockIdx.x;
    const int bond0 = blk * BM;

    const int m0 = lo, m1 = lo + 32;
    const int ia0 = conn[(bond0 + m0) * 2];
    const int ia1 = conn[(bond0 + m1) * 2];
    const unsigned oz = (unsigned)(ia0 >> 31);   // runtime 0, opaque to compiler

    const char* gw = reinterpret_cast<const char*>(w2f)
                   + (size_t)(kq * 16) * 8192 + wc * 4096 + lane * 16;
    char* lsta = reinterpret_cast<char*>(smem) + w * 16384;
    const char* lread = reinterpret_cast<const char*>(smem) + w * 16384 + lane * 16;

    f16x2 bp0[16], bp1[16];
    {
        const float* br0 = bond + (size_t)(bond0 + m0) * DIM + kq * 16;
        const float* br1 = bond + (size_t)(bond0 + m1) * DIM + kq * 16;
        #pragma unroll
        for (int q = 0; q < 4; ++q) {
            const float4 v0 = *reinterpret_cast<const float4*>(br0 + q * 4);
            const float4 v1 = *reinterpret_cast<const float4*>(br1 + q * 4);
            const f16 a0 = (f16)v0.x, a1 = (f16)v0.y, a2 = (f16)v0.z, a3 = (f16)v0.w;
            const f16 c0 = (f16)v1.x, c1 = (f16)v1.y, c2 = (f16)v1.z, c3 = (f16)v1.w;
            bp0[q*4+0] = (f16x2){a0,a0}; bp0[q*4+1] = (f16x2){a1,a1};
            bp0[q*4+2] = (f16x2){a2,a2}; bp0[q*4+3] = (f16x2){a3,a3};
            bp1[q*4+0] = (f16x2){c0,c0}; bp1[q*4+1] = (f16x2){c1,c1};
            bp1[q*4+2] = (f16x2){c2,c2}; bp1[q*4+3] = (f16x2){c3,c3};
        }
    }

    const float* ar0 = atom + (size_t)(blk >> 3) * (NATOMS * DIM) + (size_t)ia0 * DIM;
    const float* ar1 = atom + (size_t)(blk >> 3) * (NATOMS * DIM) + (size_t)ia1 * DIM;
    f16x2 srcv[2][4][4];
    #pragma unroll
    for (int s = 0; s < 4; ++s) {
        const int j0 = s * 16 + hi * 8;
        float4 p0 = *reinterpret_cast<const float4*>(ar0 + j0);
        float4 p1 = *reinterpret_cast<const float4*>(ar0 + j0 + 4);
        float4 q0 = *reinterpret_cast<const float4*>(ar1 + j0);
        float4 q1 = *reinterpret_cast<const float4*>(ar1 + j0 + 4);
        srcv[0][s][0] = (f16x2){ (f16)p0.x, (f16)p0.y };
        srcv[0][s][1] = (f16x2){ (f16)p0.z, (f16)p0.w };
        srcv[0][s][2] = (f16x2){ (f16)p1.x, (f16)p1.y };
        srcv[0][s][3] = (f16x2){ (f16)p1.z, (f16)p1.w };
        srcv[1][s][0] = (f16x2){ (f16)q0.x, (f16)q0.y };
        srcv[1][s][1] = (f16x2){ (f16)q0.z, (f16)q0.w };
        srcv[1][s][2] = (f16x2){ (f16)q1.x, (f16)q1.y };
        srcv[1][s][3] = (f16x2){ (f16)q1.z, (f16)q1.w };
    }

    #define DISSUE(itf) do { if ((itf) < 16) {                            \
        const char* _g = gw + (itf) * 8192;                               \
        char* _l = lsta + ((itf) & 3) * 4096;                             \
        gll16(_g,        _l);                                             \
        gll16(_g + 1024, _l + 1024);                                      \
        gll16(_g + 2048, _l + 2048);                                      \
        gll16(_g + 3072, _l + 3072);                                      \
    } } while (0)

    #define DSTEP(iti, wtxt) do {                                         \
        if constexpr (MODE == 0 || MODE == 2) DISSUE((iti) + 3);          \
        H8 _af0[4], _af1[4];                                              \
        {                                                                 \
            const f16x2 _c0 = bp0[iti];                                   \
            const f16x2 _c1 = bp1[iti];                                   \
            _Pragma("unroll")                                             \
            for (int s = 0; s < 4; ++s) {                                 \
                _Pragma("unroll")                                         \
                for (int t = 0; t < 4; ++t) {                             \
                    _af0[s].v2[t] = _c0 * srcv[0][s][t];                  \
                    _af1[s].v2[t] = _c1 * srcv[1][s][t];                  \
                }                                                         \
            }                                                             \
        }                                                                 \
        if constexpr (MODE == 0 || MODE == 2) {                           \
            asm volatile("s_waitcnt vmcnt(" wtxt ")" ::: "memory");       \
            __builtin_amdgcn_sched_barrier(0);                            \
        }                                                                 \
        {                                                                 \
            const char* _lr = lread + ((iti) & 3) * 4096;                 \
            _Pragma("unroll")                                             \
            for (int s = 0; s < 4; ++s) {                                 \
                f16x8 bf;                                                 \
                if constexpr (MODE == 0 || MODE == 1)                     \
                    bf = *reinterpret_cast<const f16x8*>(_lr + s * 1024); \
                else                                                      \
                    bf = _af1[s].v8;                                      \
                acc0 = __builtin_amdgcn_mfma_f32_32x32x16_f16(_af0[s].v8, bf, acc0, 0, 0, 0); \
                acc1 = __builtin_amdgcn_mfma_f32_32x32x16_f16(_af1[s].v8, bf, acc1, 0, 0, 0); \
            }                                                             \
        }                                                                 \
    } while (0)

    f32x16 acc0 = {}, acc1 = {};
    for (int rep = 0; rep < DREPS; ++rep) {
        // rep-dependent opaque init: defeats LICM of the (otherwise
        // loop-invariant) body; oz==0 at runtime so value is a denormal.
        acc0 = (f32x16){}; acc1 = (f32x16){};
        acc0[0] = __builtin_bit_cast(float, oz ^ (unsigned)rep);
        acc1[0] = __builtin_bit_cast(float, oz ^ (unsigned)(rep + 7));
        if constexpr (MODE == 0 || MODE == 2) { DISSUE(0); DISSUE(1); DISSUE(2); }
        DSTEP( 0, "12"); DSTEP( 1, "12"); DSTEP( 2, "12"); DSTEP( 3, "12");
        DSTEP( 4, "12"); DSTEP( 5, "12"); DSTEP( 6, "12"); DSTEP( 7, "12");
        DSTEP( 8, "12"); DSTEP( 9, "12"); DSTEP(10, "12"); DSTEP(11, "12");
        DSTEP(12, "12"); DSTEP(13, "8");  DSTEP(14, "4");  DSTEP(15, "0");
    }
    #undef DSTEP
    #undef DISSUE

    // keep-alive sink (scratch region; rewritten by prep next replay)
    float r = acc0[0] + acc1[0];
    #pragma unroll
    for (int g = 1; g < 16; ++g) r += acc0[g] + acc1[g];
    sink[(size_t)blk * 512 + tid] = r;
}

// ---- fallback (ws too small): f32, LDS-staged, correct.
__global__ __launch_bounds__(256) void bond_fallback(
    const float* __restrict__ atom, const float* __restrict__ bond,
    const int* __restrict__ conn, const float* __restrict__ bt,
    float* __restrict__ out)
{
    __shared__ float Wk[4096];
    __shared__ float srcs[4][64];
    __shared__ float bnds[4][64];
    const int blk = blockIdx.x;
    const int e0 = blk * 4;
    const int b = e0 >> 9;
    const int t = threadIdx.x;
    const int il = t & 63, eg = t >> 6;
    const int e = e0 + eg;
    const int ia = conn[e * 2];
    srcs[eg][il] = atom[(size_t)b * (NATOMS * DIM) + (size_t)ia * DIM + il];
    bnds[eg][il] = bond[(size_t)e * DIM + il];
    float acc = 0.f;
    for (int k = 0; k < 64; ++k) {
        __syncthreads();
        #pragma unroll
        for (int c = 0; c < 4; ++c) {
            float4 v = reinterpret_cast<const float4*>(bt + (size_t)k * 4096)[t + c * 256];
            reinterpret_cast<float4*>(Wk)[t + c * 256] = v;
        }
        __syncthreads();
        float s = 0.f;
        #pragma unroll
        for (int j = 0; j < 64; ++j) s += Wk[il * 64 + j] * srcs[eg][j];
        acc += bnds[eg][k] * s;
    }
    out[(size_t)e * DIM + il] = acc;
}

extern "C" void kernel_launch(void* const* d_in, const int* in_sizes, int n_in,
                              void* d_out, int out_size, void* d_ws, size_t ws_size,
                              hipStream_t stream) {
    const float* atom = (const float*)d_in[0];   // (32,256,64) f32
    const float* bond = (const float*)d_in[1];   // (32,512,64) f32
    const int*   conn = (const int*)d_in[2];     // (32,512,2) int32 (narrowed)
    const float* bt   = (const float*)d_in[3];   // (64,4096) f32
    float* out = (float*)d_out;                  // (32,512,64) f32

    if (ws_size >= (size_t)64 * 4096 * sizeof(f16)) {
        f16* w2f = (f16*)d_ws;                   // 512 KB scratch
        prep_w2f<<<128, 256, 0, stream>>>(bt, w2f);
        bond_msg<<<256, 512, 0, stream>>>(atom, bond, conn, w2f, out);
        // ---- ablation dispatches (scratch sink = w2f region; prep rewrites
        // it at the start of every replay, so ordering keeps d_out correct).
        float* sink = (float*)d_ws;
        bond_diag<0><<<256, 512, 0, stream>>>(atom, bond, conn, w2f, sink);
        bond_diag<1><<<256, 512, 0, stream>>>(atom, bond, conn, w2f, sink);
        bond_diag<2><<<256, 512, 0, stream>>>(atom, bond, conn, w2f, sink);
        bond_diag<3><<<256, 512, 0, stream>>>(atom, bond, conn, w2f, sink);
    } else {
        bond_fallback<<<4096, 256, 0, stream>>>(atom, bond, conn, bt, out);
    }
}

// Round 13
// 22.484 us; speedup vs baseline: 411.9057x; 411.9057x over previous
//
#include <hip/hip_runtime.h>
#include <stdint.h>

// ---------------------------------------------------------------------------
// BondMatrixMessage: messages[b,e,i] = sum_{k,j} bond[b,e,k] W[k,i,j] src[b,e,j]
// GEMM recast: C[16384 x 64] = A[16384 x 4096] @ W2[4096 x 64]
//   A[e, k*64+j] = bond[e,k]*src[e,j]  (registers, v_pk_mul_f16)
//   W2 prep-cast to f16 in MFMA-fragment order (w2f) by prep kernel.
// R13: R12 col-split with the phase-count bug fixed. R12 ran 16 phases where
// the geometry gives 8 (4 staging waves x 4 k/phase x 8 phases = 32 k per
// k-half): kh=1 read past the 512KB table (poison -> NaN) and bp[] was
// indexed OOB. Now: 256 blocks = 128 bond-tiles (BT=128) x 2 col-halves;
// each block reads 256 KB of W2 (64 MB aggregate, 2x cut vs R3-R10).
// 8 waves = 4 m-tiles x 2 k-halves; the 4 waves of a k-half SHARE one
// staged stream (4-way LDS reuse). Producer-consumer m201-style: raw
// s_barrier + counted vmcnt(4) (NOT __syncthreads), 8 phases, 2-buffer ring.
// conn is int32 (harness narrows int64): src idx = conn[e*2].
// ---------------------------------------------------------------------------

#define NATOMS 256
#define DIM 64
#define BT 128   // bonds per block

typedef _Float16 f16;
typedef _Float16 f16x2 __attribute__((ext_vector_type(2)));
typedef _Float16 f16x8 __attribute__((ext_vector_type(8)));
typedef float f32x16 __attribute__((ext_vector_type(16)));

#define AS1 __attribute__((address_space(1)))
#define AS3 __attribute__((address_space(3)))

union H8 { f16x8 v8; f16x2 v2[4]; };

static __device__ __forceinline__ void gll16(const void* g, void* l) {
    __builtin_amdgcn_global_load_lds((AS1 void*)(uintptr_t)g, (AS3 void*)l, 16, 0, 0);
}

static __device__ __forceinline__ void wave_barrier() {
    __builtin_amdgcn_sched_barrier(0);
    __builtin_amdgcn_s_barrier();
    __builtin_amdgcn_sched_barrier(0);
}

// prep: cast + permute bt (64 x 4096 f32) into col-split fragment order.
// Chunk d = k*512 + ch*256 + s*64 + l (16B each):
//   col = ch*32 + (l&31);  elems = bt[k][col*64 + s*16 + (l>>5)*8 + 0..8)
// (semantically identical content to the R10 table, which validated)
__global__ __launch_bounds__(256) void prep_w2f(const float* __restrict__ bt,
                                                f16* __restrict__ w2f) {
    const int d  = blockIdx.x * 256 + threadIdx.x;   // 32768 chunks
    const int k  = d >> 9, c = d & 511;
    const int ch = c >> 8, s = (c >> 6) & 3, l = c & 63;
    const int col = ch * 32 + (l & 31);
    const float* src = bt + (size_t)k * 4096 + col * 64 + s * 16 + (l >> 5) * 8;
    const float4 p = *reinterpret_cast<const float4*>(src);
    const float4 q = *reinterpret_cast<const float4*>(src + 4);
    const f16x8 h = { (f16)p.x, (f16)p.y, (f16)p.z, (f16)p.w,
                      (f16)q.x, (f16)q.y, (f16)q.z, (f16)q.w };
    reinterpret_cast<f16x8*>(w2f)[d] = h;
}

static __device__ __forceinline__ unsigned swz16(unsigned lane) {
    return (lane * 16u) ^ ((lane & 0x38u) << 1);
}

__global__ __launch_bounds__(512, 1) void bond_msg(
    const float* __restrict__ atom, const float* __restrict__ bond,
    const int* __restrict__ conn, const f16* __restrict__ w2f,
    float* __restrict__ out)
{
    // LDS: stage ring buf[pb(2)][kh(2)][q(4)][s(4)][64 x 16B] = 64 KB.
    //      epilogue reuses [0,16K) for kh-pair reduce.
    __shared__ __align__(16) unsigned char smem[65536];

    const int tid  = threadIdx.x;
    const int lane = tid & 63;
    const int w    = tid >> 6;     // wave 0..7
    const int mt   = w & 3;        // m-tile (32 bonds each)
    const int kh   = w >> 2;       // k half (k in [kh*32, kh*32+32))
    const int lo   = lane & 31;
    const int hi   = lane >> 5;
    const int blk  = blockIdx.x;
    const int btile = blk >> 1;    // bond tile 0..127
    const int ch   = blk & 1;      // column half (32 cols)
    const int bond0 = btile * BT;  // 4 tiles per batch; never straddles

    // ---- stage pipeline bases
    // w2f bytes: k*8192 + ch*4096 + s*1024 + lane*16
    const char* gw = reinterpret_cast<const char*>(w2f)
                   + (size_t)ch * 4096 + (size_t)lane * 16;
    char* lst = reinterpret_cast<char*>(smem) + kh * 16384 + mt * 4096; // wave-uniform
    const char* lrd = reinterpret_cast<const char*>(smem) + kh * 16384 + lane * 16;

    // wave (mt,kh) stages kg = kh*32 + p*4 + mt for phase p in [0,8)
    #define ISSUE(p) do {                                                 \
        const char* _g = gw + (size_t)(kh * 32 + (p) * 4 + mt) * 8192;    \
        char* _l = lst + ((p) & 1) * 32768;                               \
        gll16(_g,        _l);                                             \
        gll16(_g + 1024, _l + 1024);                                      \
        gll16(_g + 2048, _l + 2048);                                      \
        gll16(_g + 3072, _l + 3072);                                      \
    } while (0)

    ISSUE(0);   // start pipeline before the gather chain

    // ---- this wave's bond row e and its 32 k-values (dup'd f16 pairs)
    const int e = bond0 + mt * 32 + lo;
    const int ia = conn[e * 2];
    f16x2 bp[32];
    {
        const float* brow = bond + (size_t)e * DIM + kh * 32;
        #pragma unroll
        for (int q = 0; q < 8; ++q) {
            const float4 v = *reinterpret_cast<const float4*>(brow + q * 4);
            const f16 a0 = (f16)v.x, a1 = (f16)v.y, a2 = (f16)v.z, a3 = (f16)v.w;
            bp[q*4+0] = (f16x2){a0,a0}; bp[q*4+1] = (f16x2){a1,a1};
            bp[q*4+2] = (f16x2){a2,a2}; bp[q*4+3] = (f16x2){a3,a3};
        }
    }

    // ---- src atom row -> registers (f16 pairs); j = s*16 + hi*8 + {0..7}
    const float* arow = atom + (size_t)(btile >> 2) * (NATOMS * DIM)
                      + (size_t)ia * DIM;
    f16x2 srcv[4][4];
    #pragma unroll
    for (int s = 0; s < 4; ++s) {
        const int j0 = s * 16 + hi * 8;
        const float4 p0 = *reinterpret_cast<const float4*>(arow + j0);
        const float4 p1 = *reinterpret_cast<const float4*>(arow + j0 + 4);
        srcv[s][0] = (f16x2){ (f16)p0.x, (f16)p0.y };
        srcv[s][1] = (f16x2){ (f16)p0.z, (f16)p0.w };
        srcv[s][2] = (f16x2){ (f16)p1.x, (f16)p1.y };
        srcv[s][3] = (f16x2){ (f16)p1.z, (f16)p1.w };
    }

    // ---- main loop: 8 phases x 4 kg x 4 s; producer-consumer, counted vmcnt
    f32x16 acc = {};

    #define STEP(p, wtxt) do {                                            \
        if ((p) + 1 < 8) ISSUE((p) + 1);                                  \
        asm volatile("s_waitcnt vmcnt(" wtxt ")" ::: "memory");           \
        wave_barrier();   /* all 4 kh-waves' phase-p slices landed */     \
        {                                                                 \
            const char* _rb = lrd + ((p) & 1) * 32768;                    \
            _Pragma("unroll")                                             \
            for (int q = 0; q < 4; ++q) {                                 \
                const f16x2 _c = bp[(p) * 4 + q];                         \
                _Pragma("unroll")                                         \
                for (int s = 0; s < 4; ++s) {                             \
                    const f16x8 bf = *reinterpret_cast<const f16x8*>(     \
                        _rb + q * 4096 + s * 1024);                       \
                    H8 _a;                                                \
                    _Pragma("unroll")                                     \
                    for (int t = 0; t < 4; ++t) _a.v2[t] = _c * srcv[s][t]; \
                    acc = __builtin_amdgcn_mfma_f32_32x32x16_f16(_a.v8, bf, acc, 0, 0, 0); \
                }                                                         \
            }                                                             \
        }                                                                 \
        wave_barrier();   /* buffer ring reuse safe */                    \
    } while (0)

    STEP(0, "4"); STEP(1, "4"); STEP(2, "4"); STEP(3, "4");
    STEP(4, "4"); STEP(5, "4"); STEP(6, "4"); STEP(7, "0");

    #undef STEP
    #undef ISSUE

    // ---- epilogue: kh-pair reduce through LDS [0,16K), kh=0 writes C
    __syncthreads();
    if (kh == 1) {
        const unsigned so = swz16((unsigned)lane);
        #pragma unroll
        for (int g = 0; g < 4; ++g) {
            float4 v = { acc[4*g+0], acc[4*g+1], acc[4*g+2], acc[4*g+3] };
            *reinterpret_cast<float4*>(smem + mt*4096 + g*1024 + so) = v;
        }
    }
    __syncthreads();
    if (kh == 0) {
        const unsigned so = swz16((unsigned)lane);
        #pragma unroll
        for (int g = 0; g < 4; ++g) {
            const float4 v = *reinterpret_cast<const float4*>(
                smem + mt*4096 + g*1024 + so);
            acc[4*g+0] += v.x; acc[4*g+1] += v.y;
            acc[4*g+2] += v.z; acc[4*g+3] += v.w;
        }
        const int colb = ch * 32 + lo;
        #pragma unroll
        for (int r = 0; r < 16; ++r) {
            // C/D map: col = lane&31, row = (r&3) + 8*(r>>2) + 4*(lane>>5)
            const int rl = (r & 3) + 8 * (r >> 2) + 4 * hi;
            out[(size_t)(bond0 + mt * 32 + rl) * 64 + colb] = acc[r];
        }
    }
}

// ---- fallback (ws too small): f32, LDS-staged, correct.
__global__ __launch_bounds__(256) void bond_fallback(
    const float* __restrict__ atom, const float* __restrict__ bond,
    const int* __restrict__ conn, const float* __restrict__ bt,
    float* __restrict__ out)
{
    __shared__ float Wk[4096];
    __shared__ float srcs[4][64];
    __shared__ float bnds[4][64];
    const int blk = blockIdx.x;
    const int e0 = blk * 4;
    const int b = e0 >> 9;
    const int t = threadIdx.x;
    const int il = t & 63, eg = t >> 6;
    const int e = e0 + eg;
    const int ia = conn[e * 2];
    srcs[eg][il] = atom[(size_t)b * (NATOMS * DIM) + (size_t)ia * DIM + il];
    bnds[eg][il] = bond[(size_t)e * DIM + il];
    float acc = 0.f;
    for (int k = 0; k < 64; ++k) {
        __syncthreads();
        #pragma unroll
        for (int c = 0; c < 4; ++c) {
            float4 v = reinterpret_cast<const float4*>(bt + (size_t)k * 4096)[t + c * 256];
            reinterpret_cast<float4*>(Wk)[t + c * 256] = v;
        }
        __syncthreads();
        float s = 0.f;
        #pragma unroll
        for (int j = 0; j < 64; ++j) s += Wk[il * 64 + j] * srcs[eg][j];
        acc += bnds[eg][k] * s;
    }
    out[(size_t)e * DIM + il] = acc;
}

extern "C" void kernel_launch(void* const* d_in, const int* in_sizes, int n_in,
                              void* d_out, int out_size, void* d_ws, size_t ws_size,
                              hipStream_t stream) {
    const float* atom = (const float*)d_in[0];   // (32,256,64) f32
    const float* bond = (const float*)d_in[1];   // (32,512,64) f32
    const int*   conn = (const int*)d_in[2];     // (32,512,2) int32 (narrowed)
    const float* bt   = (const float*)d_in[3];   // (64,4096) f32
    float* out = (float*)d_out;                  // (32,512,64) f32

    if (ws_size >= (size_t)64 * 4096 * sizeof(f16)) {
        f16* w2f = (f16*)d_ws;                   // 512 KB scratch
        prep_w2f<<<128, 256, 0, stream>>>(bt, w2f);
        bond_msg<<<256, 512, 0, stream>>>(atom, bond, conn, w2f, out);
    } else {
        bond_fallback<<<4096, 256, 0, stream>>>(atom, bond, conn, bt, out);
    }
}